// Round 2
// baseline (317.818 us; speedup 1.0000x reference)
//
#include <hip/hip_runtime.h>

// Problem constants
#define BB 64
#define CC 3
#define HH 512
#define WW 512
#define PP 16
#define IN_F 256
#define HD 512
#define PATCH_DIM 768   // 16*16*3
#define NPATCH 1024     // 32*32
#define NB_M3 257       // 256 blocks x 3 rows of M3, +1 block for c3

// native clang vector for nontemporal builtin (HIP float4 is a struct -> rejected)
typedef float floatx4 __attribute__((ext_vector_type(4)));

// ---------------------------------------------------------------------------
// Math collapse: softmax over a size-1 axis == 1, so attn is all-ones and
//   out[b,h,d] = sum_n feat_h[b,h,n,d]
// Linearity lets the patch-sum move to the front, and the whole weight chain
// pre-associates:
//   S[b,k]   = sum_{h,w} feature[b, c, 16h+p1, 16w+p2],  k=(p1*16+p2)*3+c
//   M3       = W_patch @ W @ W_out                  (768x256, weights-only)
//   c3       = 1024*(b_patch @ W @ W_out) + b_out   (256,   weights-only)
//   z        = S @ M3 + c3                          (single GEMV per batch)
//   x        = 0.25*z + 0.75*token
//   out      = LayerNorm(x)*gamma + beta
// M3/c3 have no dependency on S -> computed in the SAME launch as the patch
// reduction (heterogeneous grid, M3 blocks first so they hide under the
// HBM-bound feature streaming).
// ---------------------------------------------------------------------------

// Kernel 1 (merged):
//   blocks [0, 257)    : M3 rows / c3   (L2/VALU-bound, overlaps patch)
//   blocks [257, 3329) : patch reduce   (HBM-bound, 201 MB compulsory)
__global__ __launch_bounds__(256)
void prep_kernel(const float* __restrict__ feature,
                 const float* __restrict__ Wp,
                 const float* __restrict__ bp,
                 const float* __restrict__ W,
                 const float* __restrict__ Wo,
                 const float* __restrict__ bo,
                 float* __restrict__ S,
                 float* __restrict__ M3,
                 float* __restrict__ c3)
{
    int bid = blockIdx.x;
    int t = threadIdx.x;

    if (bid < NB_M3) {
        // ---- M3 path: rows i0..i0+2 of M3 = Wp @ W @ Wo (or the bp row) ----
        __shared__ float sWp[3][IN_F];   // 3 KB
        __shared__ float sv[3][HD];      // 6 KB

        if (bid < 256) {
            int i0 = bid * 3;
            sWp[0][t] = Wp[(size_t)(i0 + 0) * IN_F + t];
            sWp[1][t] = Wp[(size_t)(i0 + 1) * IN_F + t];
            sWp[2][t] = Wp[(size_t)(i0 + 2) * IN_F + t];
        } else {
            sWp[0][t] = bp[t];
            sWp[1][t] = 0.f;
            sWp[2][t] = 0.f;
        }
        __syncthreads();

        // Phase A: v[r][l] = sum_k sWp[r][k] * W[k][l]; thread t owns l=2t,2t+1.
        // One float2 stream of W shared by all 3 rows (W read once per block).
        float a00 = 0.f, a01 = 0.f, a10 = 0.f, a11 = 0.f, a20 = 0.f, a21 = 0.f;
        const float* wb = W + 2 * t;
#pragma unroll 8
        for (int k = 0; k < IN_F; ++k) {
            float2 w = *(const float2*)(wb + (size_t)k * HD);
            float s0 = sWp[0][k], s1 = sWp[1][k], s2 = sWp[2][k];
            a00 += s0 * w.x; a01 += s0 * w.y;
            a10 += s1 * w.x; a11 += s1 * w.y;
            a20 += s2 * w.x; a21 += s2 * w.y;
        }
        sv[0][2 * t] = a00; sv[0][2 * t + 1] = a01;
        sv[1][2 * t] = a10; sv[1][2 * t + 1] = a11;
        sv[2][2 * t] = a20; sv[2][2 * t + 1] = a21;
        __syncthreads();

        // Phase B: M3[i_r][j] = sum_l v[r][l] * Wo[l][j]; thread t owns j=t.
        float b0 = 0.f, b1 = 0.f, b2 = 0.f;
        const float* wob = Wo + t;
#pragma unroll 8
        for (int l = 0; l < HD; ++l) {
            float w = wob[(size_t)l * IN_F];
            b0 += sv[0][l] * w;
            b1 += sv[1][l] * w;
            b2 += sv[2][l] * w;
        }
        if (bid < 256) {
            int i0 = bid * 3;
            M3[(size_t)(i0 + 0) * IN_F + t] = b0;
            M3[(size_t)(i0 + 1) * IN_F + t] = b1;
            M3[(size_t)(i0 + 2) * IN_F + t] = b2;
        } else {
            c3[t] = 1024.f * b0 + bo[t];   // folds b_out too
        }
        return;
    }

    // ---- Patch-reduce path (unchanged, proven):
    // S[b, (p1*16+p2)*3 + c] = sum_{h,w} feature[b, c, 16h+p1, 16w+p2]
    {
        int pbid = bid - NB_M3;
        int p1 = pbid & 15;
        int tmp = pbid >> 4;
        int c = tmp % 3;
        int b = tmp / 3;

        const size_t base_bc = (size_t)(b * 3 + c) * (size_t)(HH * WW);

        float acc[4] = {0.f, 0.f, 0.f, 0.f};

#pragma unroll
        for (int i = 0; i < 16; ++i) {
            int idx = i * 256 + t;        // 0..4095
            int h = idx >> 7;             // 0..31
            int u = idx & 127;            // float4-chunk within row
            size_t off = base_bc + (size_t)(p1 + 16 * h) * WW + (size_t)u * 4;
            floatx4 v = __builtin_nontemporal_load((const floatx4*)(feature + off));
            acc[0] += v.x;
            acc[1] += v.y;
            acc[2] += v.z;
            acc[3] += v.w;
        }

        __shared__ float red[16 * 68];
        __shared__ float red2[16 * 8];
        int g = t >> 2;                  // 0..63
        int pb = (t & 3) * 4;
#pragma unroll
        for (int j = 0; j < 4; ++j)
            red[(pb + j) * 68 + g] = acc[j];
        __syncthreads();

        if (t < 128) {
            int bin = t >> 3;
            int l = t & 7;
            float s = 0.f;
#pragma unroll
            for (int q = 0; q < 8; ++q)
                s += red[bin * 68 + l + 8 * q];
            red2[bin * 8 + l] = s;
        }
        __syncthreads();

        if (t < 16) {
            float s = 0.f;
#pragma unroll
            for (int l = 0; l < 8; ++l)
                s += red2[t * 8 + l];
            S[(size_t)b * PATCH_DIM + (size_t)(p1 * 16 + t) * 3 + c] = s;
        }
    }
}

// Kernel 2: per-batch single-GEMV chain + LayerNorm.
// grid = 64 blocks, 512 threads (8 waves).
__global__ __launch_bounds__(512)
void fuse_kernel(const float* __restrict__ S,
                 const float* __restrict__ M3,
                 const float* __restrict__ c3,
                 const float* __restrict__ tok,
                 const float* __restrict__ gamma,
                 const float* __restrict__ beta,
                 float* __restrict__ out)
{
    int b = blockIdx.x;
    int t = threadIdx.x;

    __shared__ float sS[PATCH_DIM];         // 768
    __shared__ float part[8 * IN_F];        // GEMV partials [kg][256]
    __shared__ float wred[8];
    __shared__ float stats[2];

    float c3_t = 0.f, tok_t = 0.f, gamma_t = 0.f, beta_t = 0.f;
    if (t < IN_F) {
        c3_t    = c3[t];
        tok_t   = tok[b * IN_F + t];
        gamma_t = gamma[t];
        beta_t  = beta[t];
    }

    for (int k = t; k < PATCH_DIM; k += 512)
        sS[k] = S[(size_t)b * PATCH_DIM + k];
    __syncthreads();

    // ---- z = S @ M3   (768 -> 256), split k over 8 groups of 96 ----
    {
        int j4 = (t & 63) * 4;
        int kg = t >> 6;              // 0..7, k in [kg*96, +96)
        float a0 = 0.f, a1 = 0.f, a2 = 0.f, a3 = 0.f;
        const float* wrow = M3 + (size_t)(kg * 96) * IN_F + j4;
#pragma unroll 8
        for (int i = 0; i < 96; ++i) {
            float s = sS[kg * 96 + i];
            float4 w = *(const float4*)(wrow + (size_t)i * IN_F);
            a0 += s * w.x; a1 += s * w.y; a2 += s * w.z; a3 += s * w.w;
        }
        part[kg * IN_F + j4 + 0] = a0;
        part[kg * IN_F + j4 + 1] = a1;
        part[kg * IN_F + j4 + 2] = a2;
        part[kg * IN_F + j4 + 3] = a3;
    }
    __syncthreads();

    // ---- Epilogue (threads 0..255): residual + LayerNorm ----
    float x = 0.f;
    if (t < IN_F) {
        float z = 0.f;
#pragma unroll
        for (int kg = 0; kg < 8; ++kg)
            z += part[kg * IN_F + t];
        x = 0.25f * (z + c3_t) + 0.75f * tok_t;
    }

    float s1 = x, s2 = x * x;     // zero for t>=256
#pragma unroll
    for (int off = 32; off > 0; off >>= 1) {
        s1 += __shfl_down(s1, off);
        s2 += __shfl_down(s2, off);
    }
    int wave = t >> 6;
    if ((t & 63) == 0 && wave < 4) {   // only waves 0..3 hold real data
        wred[wave * 2]     = s1;
        wred[wave * 2 + 1] = s2;
    }
    __syncthreads();
    if (t == 0) {
        float a1 = wred[0] + wred[2] + wred[4] + wred[6];
        float a2 = wred[1] + wred[3] + wred[5] + wred[7];
        float mu = a1 * (1.f / 256.f);
        float var = a2 * (1.f / 256.f) - mu * mu;
        stats[0] = mu;
        stats[1] = rsqrtf(var + 1e-5f);
    }
    __syncthreads();

    if (t < IN_F) {
        float y = (x - stats[0]) * stats[1] * gamma_t + beta_t;
        out[b * IN_F + t] = y;
    }
}

extern "C" void kernel_launch(void* const* d_in, const int* in_sizes, int n_in,
                              void* d_out, int out_size, void* d_ws, size_t ws_size,
                              hipStream_t stream)
{
    const float* token   = (const float*)d_in[0];
    const float* feature = (const float*)d_in[1];
    const float* W_patch = (const float*)d_in[2];
    const float* b_patch = (const float*)d_in[3];
    const float* W       = (const float*)d_in[4];
    // d_in[5] = a_self, d_in[6] = a_neigh : dead (softmax over size-1 axis == 1)
    const float* W_out   = (const float*)d_in[7];
    const float* b_out   = (const float*)d_in[8];
    const float* gamma   = (const float*)d_in[9];
    const float* beta    = (const float*)d_in[10];

    float* out = (float*)d_out;
    float* S  = (float*)d_ws;                       // 64*768 floats
    float* M3 = S + (size_t)BB * PATCH_DIM;         // 768*256 floats
    float* c3 = M3 + (size_t)PATCH_DIM * IN_F;      // 256 floats (~984 KB total)

    // Launch 1: M3/c3 (weights-only, blocks 0..256) + patch reduce (rest).
    dim3 grid1(NB_M3 + BB * CC * 16);
    prep_kernel<<<grid1, 256, 0, stream>>>(feature, W_patch, b_patch,
                                           W, W_out, b_out, S, M3, c3);

    // Launch 2: per-batch GEMV + LayerNorm.
    fuse_kernel<<<BB, 512, 0, stream>>>(S, M3, c3, token, gamma, beta, out);
}

// Round 3
// 295.823 us; speedup vs baseline: 1.0744x; 1.0744x over previous
//
#include <hip/hip_runtime.h>

// Problem constants
#define BB 64
#define CC 3
#define HH 512
#define WW 512
#define PP 16
#define IN_F 256
#define HD 512
#define PATCH_DIM 768   // 16*16*3
#define NPATCH 1024     // 32*32
#define NB_M2 512       // 256 rows x 2 col-tiles of 128

// native clang vector for nontemporal builtin (HIP float4 is a struct -> rejected)
typedef float floatx4 __attribute__((ext_vector_type(4)));

// ---------------------------------------------------------------------------
// Math collapse: softmax over a size-1 axis == 1, so attn is all-ones and
//   out[b,h,d] = sum_n feat_h[b,h,n,d]
// Linearity lets the patch-sum move to the front, and Wm@Wo pre-associates:
//   S[b,k]   = sum_{h,w} feature[b, c, 16h+p1, 16w+p2],  k=(p1*16+p2)*3+c
//   M2       = W @ W_out                          (256x256, weights-only)
//   t1       = S @ W_patch + 1024*b_patch         (768 -> 256)
//   z        = t1 @ M2                            (256 -> 256)
//   x        = 0.25*(z + b_out) + 0.75*token
//   out      = LayerNorm(x)*gamma + beta
//
// M2 has no dependency on the patch reduce -> computed in the SAME launch
// (heterogeneous grid). Lesson from last round: the weights-path blocks must
// be SHORT (fine-sharded) or they become the critical path when the 201 MB
// patch stream evicts W/W_out from L2. Here each M2 block does only 128
// coalesced float2 iterations (~2-3 us) vs the patch stream's ~32 us.
// ---------------------------------------------------------------------------

// Kernel 1 (merged):
//   blocks [0, 512)     : M2 tile (row i = bid>>1, col-tile ct = bid&1)
//   blocks [512, 3584)  : patch reduce (HBM-bound, 201 MB compulsory)
__global__ __launch_bounds__(256)
void prep_kernel(const float* __restrict__ feature,
                 const float* __restrict__ W,
                 const float* __restrict__ Wo,
                 float* __restrict__ S,
                 float* __restrict__ M2)
{
    int bid = blockIdx.x;
    int t = threadIdx.x;

    if (bid < NB_M2) {
        // ---- M2 path: M2[i, ct*128 .. +128) = sum_k W[i,k] * Wo[k, ...] ----
        __shared__ float sW[HD];            // W row i (512 floats, 2 KB)
        __shared__ float part[4][128];      // [kg][col] partials (2 KB)

        int i  = bid >> 1;
        int ct = bid & 1;

        sW[t]       = W[(size_t)i * HD + t];
        sW[t + 256] = W[(size_t)i * HD + t + 256];
        __syncthreads();

        int tc = t & 63;          // thread-col slot (owns 2 cols)
        int kg = t >> 6;          // 0..3, k-range [kg*128, +128)
        int j  = ct * 128 + tc * 2;

        float a0 = 0.f, a1 = 0.f;
        const float* wb = Wo + j;
#pragma unroll 8
        for (int k = kg * 128; k < kg * 128 + 128; ++k) {
            float2 w = *(const float2*)(wb + (size_t)k * IN_F);
            float s = sW[k];
            a0 += s * w.x;
            a1 += s * w.y;
        }
        part[kg][tc * 2]     = a0;
        part[kg][tc * 2 + 1] = a1;
        __syncthreads();

        if (t < 128) {
            float s = part[0][t] + part[1][t] + part[2][t] + part[3][t];
            M2[(size_t)i * IN_F + ct * 128 + t] = s;
        }
        return;
    }

    // ---- Patch-reduce path (unchanged, proven):
    // S[b, (p1*16+p2)*3 + c] = sum_{h,w} feature[b, c, 16h+p1, 16w+p2]
    {
        int pbid = bid - NB_M2;
        int p1 = pbid & 15;
        int tmp = pbid >> 4;
        int c = tmp % 3;
        int b = tmp / 3;

        const size_t base_bc = (size_t)(b * 3 + c) * (size_t)(HH * WW);

        float acc[4] = {0.f, 0.f, 0.f, 0.f};

#pragma unroll
        for (int i = 0; i < 16; ++i) {
            int idx = i * 256 + t;        // 0..4095
            int h = idx >> 7;             // 0..31
            int u = idx & 127;            // float4-chunk within row
            size_t off = base_bc + (size_t)(p1 + 16 * h) * WW + (size_t)u * 4;
            floatx4 v = __builtin_nontemporal_load((const floatx4*)(feature + off));
            acc[0] += v.x;
            acc[1] += v.y;
            acc[2] += v.z;
            acc[3] += v.w;
        }

        __shared__ float red[16 * 68];
        __shared__ float red2[16 * 8];
        int g = t >> 2;                  // 0..63
        int pb = (t & 3) * 4;
#pragma unroll
        for (int j = 0; j < 4; ++j)
            red[(pb + j) * 68 + g] = acc[j];
        __syncthreads();

        if (t < 128) {
            int bin = t >> 3;
            int l = t & 7;
            float s = 0.f;
#pragma unroll
            for (int q = 0; q < 8; ++q)
                s += red[bin * 68 + l + 8 * q];
            red2[bin * 8 + l] = s;
        }
        __syncthreads();

        if (t < 16) {
            float s = 0.f;
#pragma unroll
            for (int l = 0; l < 8; ++l)
                s += red2[t * 8 + l];
            S[(size_t)b * PATCH_DIM + (size_t)(p1 * 16 + t) * 3 + c] = s;
        }
    }
}

// Kernel 2: per-batch fused chain, TWO GEMV stages (Wp then M2) — proven.
// grid = 64 blocks, 512 threads (8 waves).
__global__ __launch_bounds__(512)
void fuse_kernel(const float* __restrict__ S,
                 const float* __restrict__ Wp,
                 const float* __restrict__ bp,
                 const float* __restrict__ M2,
                 const float* __restrict__ bo,
                 const float* __restrict__ tok,
                 const float* __restrict__ gamma,
                 const float* __restrict__ beta,
                 float* __restrict__ out)
{
    int b = blockIdx.x;
    int t = threadIdx.x;

    __shared__ float sS[PATCH_DIM];         // 768
    __shared__ float part1[8 * IN_F];       // stage-1 partials [kg][256]
    __shared__ float sT[IN_F];              // 256
    __shared__ float part2[8 * IN_F];       // stage-2 partials [kg][256]
    __shared__ float wred[8];
    __shared__ float stats[2];

    float bo_t = 0.f, tok_t = 0.f, gamma_t = 0.f, beta_t = 0.f, bp_t = 0.f;
    if (t < IN_F) {
        bo_t    = bo[t];
        tok_t   = tok[b * IN_F + t];
        gamma_t = gamma[t];
        beta_t  = beta[t];
        bp_t    = bp[t];
    }

    for (int k = t; k < PATCH_DIM; k += 512)
        sS[k] = S[(size_t)b * PATCH_DIM + k];
    __syncthreads();

    // ---- Stage 1: t1 = S @ Wp + 1024*bp  (768 -> 256) ----
    {
        int j4 = (t & 63) * 4;
        int kg = t >> 6;              // 0..7, k in [kg*96, +96)
        float a0 = 0.f, a1 = 0.f, a2 = 0.f, a3 = 0.f;
        const float* wrow = Wp + (size_t)(kg * 96) * IN_F + j4;
#pragma unroll 8
        for (int i = 0; i < 96; ++i) {
            float s = sS[kg * 96 + i];
            float4 w = *(const float4*)(wrow + (size_t)i * IN_F);
            a0 += s * w.x; a1 += s * w.y; a2 += s * w.z; a3 += s * w.w;
        }
        part1[kg * IN_F + j4 + 0] = a0;
        part1[kg * IN_F + j4 + 1] = a1;
        part1[kg * IN_F + j4 + 2] = a2;
        part1[kg * IN_F + j4 + 3] = a3;
    }
    __syncthreads();
    if (t < IN_F) {
        float s = 0.f;
#pragma unroll
        for (int kg = 0; kg < 8; ++kg)
            s += part1[kg * IN_F + t];
        sT[t] = s + 1024.f * bp_t;
    }
    __syncthreads();

    // ---- Stage 2: z = t1 @ M2  (256 -> 256) ----
    {
        int j4 = (t & 63) * 4;
        int kg = t >> 6;              // 0..7, k in [kg*32, +32)
        float a0 = 0.f, a1 = 0.f, a2 = 0.f, a3 = 0.f;
        const float* wrow = M2 + (size_t)(kg * 32) * IN_F + j4;
#pragma unroll 8
        for (int i = 0; i < 32; ++i) {
            float s = sT[kg * 32 + i];
            float4 w = *(const float4*)(wrow + (size_t)i * IN_F);
            a0 += s * w.x; a1 += s * w.y; a2 += s * w.z; a3 += s * w.w;
        }
        part2[kg * IN_F + j4 + 0] = a0;
        part2[kg * IN_F + j4 + 1] = a1;
        part2[kg * IN_F + j4 + 2] = a2;
        part2[kg * IN_F + j4 + 3] = a3;
    }
    __syncthreads();

    // ---- Epilogue (threads 0..255): residual + LayerNorm ----
    float x = 0.f;
    if (t < IN_F) {
        float z = 0.f;
#pragma unroll
        for (int kg = 0; kg < 8; ++kg)
            z += part2[kg * IN_F + t];
        x = 0.25f * (z + bo_t) + 0.75f * tok_t;
    }

    float s1 = x, s2 = x * x;     // zero for t>=256
#pragma unroll
    for (int off = 32; off > 0; off >>= 1) {
        s1 += __shfl_down(s1, off);
        s2 += __shfl_down(s2, off);
    }
    int wave = t >> 6;
    if ((t & 63) == 0 && wave < 4) {   // only waves 0..3 hold real data
        wred[wave * 2]     = s1;
        wred[wave * 2 + 1] = s2;
    }
    __syncthreads();
    if (t == 0) {
        float a1 = wred[0] + wred[2] + wred[4] + wred[6];
        float a2 = wred[1] + wred[3] + wred[5] + wred[7];
        float mu = a1 * (1.f / 256.f);
        float var = a2 * (1.f / 256.f) - mu * mu;
        stats[0] = mu;
        stats[1] = rsqrtf(var + 1e-5f);
    }
    __syncthreads();

    if (t < IN_F) {
        float y = (x - stats[0]) * stats[1] * gamma_t + beta_t;
        out[b * IN_F + t] = y;
    }
}

extern "C" void kernel_launch(void* const* d_in, const int* in_sizes, int n_in,
                              void* d_out, int out_size, void* d_ws, size_t ws_size,
                              hipStream_t stream)
{
    const float* token   = (const float*)d_in[0];
    const float* feature = (const float*)d_in[1];
    const float* W_patch = (const float*)d_in[2];
    const float* b_patch = (const float*)d_in[3];
    const float* W       = (const float*)d_in[4];
    // d_in[5] = a_self, d_in[6] = a_neigh : dead (softmax over size-1 axis == 1)
    const float* W_out   = (const float*)d_in[7];
    const float* b_out   = (const float*)d_in[8];
    const float* gamma   = (const float*)d_in[9];
    const float* beta    = (const float*)d_in[10];

    float* out = (float*)d_out;
    float* S  = (float*)d_ws;                 // 64*768 floats
    float* M2 = S + (size_t)BB * PATCH_DIM;   // 256*256 floats (~453 KB total)

    // Launch 1: fine-sharded M2 (blocks 0..511, ~2-3 us each) overlapped with
    // the HBM-bound patch reduce (blocks 512..3583, ~32 us total).
    dim3 grid1(NB_M2 + BB * CC * 16);
    prep_kernel<<<grid1, 256, 0, stream>>>(feature, W, W_out, S, M2);

    // Launch 2: per-batch two-stage GEMV + LayerNorm.
    fuse_kernel<<<BB, 512, 0, stream>>>(S, W_patch, b_patch, M2, b_out,
                                        token, gamma, beta, out);
}